// Round 1
// baseline (2370.885 us; speedup 1.0000x reference)
//
#include <hip/hip_runtime.h>
#include <hip/hip_bf16.h>

#define HID 512
#define B2V 8192
#define NBATCH 4096
#define TSTEPS 20

typedef __bf16 bf16x8 __attribute__((ext_vector_type(8)));
typedef float f32x4 __attribute__((ext_vector_type(4)));
typedef unsigned short u16;

__device__ __forceinline__ u16 f2bf(float f) {
  unsigned u = __builtin_bit_cast(unsigned, f);
  u = (u + 0x7FFFu + ((u >> 16) & 1u)) >> 16;   // RNE
  return (u16)u;
}
__device__ __forceinline__ bf16x8 ldb(const u16* p) {
  return *reinterpret_cast<const bf16x8*>(p);
}
__device__ __forceinline__ float sig_(float v) { return 1.f / (1.f + __expf(-v)); }
__device__ __forceinline__ float tanh_(float v) { return 1.f - 2.f / (1.f + __expf(2.f * v)); }

#define MFMA16(a, b, c) __builtin_amdgcn_mfma_f32_16x16x32_bf16((a), (b), (c), 0, 0, 0)

// ---------------- prep kernels ----------------
__global__ void convert_f32_bf16(const float* __restrict__ s, u16* __restrict__ d, int n) {
  int i = (blockIdx.x * blockDim.x + threadIdx.x) * 4;
  if (i + 3 < n) {
    float4 v = *reinterpret_cast<const float4*>(s + i);
    ushort4 o;
    o.x = f2bf(v.x); o.y = f2bf(v.y); o.z = f2bf(v.z); o.w = f2bf(v.w);
    *reinterpret_cast<ushort4*>(d + i) = o;
  }
}

__global__ void init_state(const float* __restrict__ h0, const float* __restrict__ c0,
                           u16* __restrict__ hbf, float* __restrict__ cws,
                           float* __restrict__ acc, int n, int nacc) {
  int i = blockIdx.x * blockDim.x + threadIdx.x;
  if (i < n) { hbf[i] = f2bf(h0[i]); cws[i] = c0[i]; }
  if (i < nacc) acc[i] = 0.f;
}

// ---------------- LSTM step: gates GEMM + activations fused ----------------
// grid: 64 n-blocks (128 rows each) x 16 u-blocks (32 cols each) = 1024 blocks, 256 thr.
// wave w owns rows [n0+32w, n0+32w+32) x u-tile [u0,u0+32), computes all 4 gates.
__global__ __launch_bounds__(256, 2) void lstm_step(
    const u16* __restrict__ Whh,    // [2048][512] bf16
    const float* __restrict__ Wih,  // [2048][2]
    const float* __restrict__ bih, const float* __restrict__ bhh,
    const float* __restrict__ x,    // [8192][20][2]
    const u16* __restrict__ hin,    // [8192][512] bf16
    u16* __restrict__ hout,         // [8192][512] bf16
    float* __restrict__ c,          // [8192][512] f32 (in/out)
    int t) {
  const int lane = threadIdx.x & 63;
  const int wid = threadIdx.x >> 6;
  const int u0 = (blockIdx.x & 15) * 32;
  const int n0 = (blockIdx.x >> 4) * 128 + wid * 32;
  const int jl = lane & 15;
  const int kg = (lane >> 4) * 8;

  const u16* ap0 = hin + (n0 + jl) * HID + kg;
  const u16* ap1 = ap0 + 16 * HID;
  const u16* bbase = Whh + (u0 + jl) * HID + kg;

  f32x4 acc[4][2][2];
#pragma unroll
  for (int g = 0; g < 4; ++g)
#pragma unroll
    for (int m = 0; m < 2; ++m)
#pragma unroll
      for (int nf = 0; nf < 2; ++nf) acc[g][m][nf] = (f32x4){0.f, 0.f, 0.f, 0.f};

#pragma unroll 2
  for (int k0 = 0; k0 < HID; k0 += 32) {
    bf16x8 a0 = ldb(ap0 + k0);
    bf16x8 a1 = ldb(ap1 + k0);
#pragma unroll
    for (int g = 0; g < 4; ++g) {
#pragma unroll
      for (int nf = 0; nf < 2; ++nf) {
        bf16x8 b = ldb(bbase + (g * 512 + nf * 16) * HID + k0);
        acc[g][0][nf] = MFMA16(a0, b, acc[g][0][nf]);
        acc[g][1][nf] = MFMA16(a1, b, acc[g][1][nf]);
      }
    }
  }

  // extra terms (x @ W_ih^T + biases), per (gate, nf) — n-independent parts
  float eb[4][2], w0[4][2], w1[4][2];
#pragma unroll
  for (int g = 0; g < 4; ++g)
#pragma unroll
    for (int nf = 0; nf < 2; ++nf) {
      int j = g * 512 + u0 + nf * 16 + jl;
      eb[g][nf] = bih[j] + bhh[j];
      w0[g][nf] = Wih[j * 2 + 0];
      w1[g][nf] = Wih[j * 2 + 1];
    }

#pragma unroll
  for (int m = 0; m < 2; ++m) {
#pragma unroll
    for (int r = 0; r < 4; ++r) {
      int n = n0 + m * 16 + (lane >> 4) * 4 + r;
      float x0 = x[n * 40 + t * 2 + 0];
      float x1 = x[n * 40 + t * 2 + 1];
#pragma unroll
      for (int nf = 0; nf < 2; ++nf) {
        int u = u0 + nf * 16 + jl;
        float gi = acc[0][m][nf][r] + eb[0][nf] + x0 * w0[0][nf] + x1 * w1[0][nf];
        float gf = acc[1][m][nf][r] + eb[1][nf] + x0 * w0[1][nf] + x1 * w1[1][nf];
        float gg = acc[2][m][nf][r] + eb[2][nf] + x0 * w0[2][nf] + x1 * w1[2][nf];
        float go = acc[3][m][nf][r] + eb[3][nf] + x0 * w0[3][nf] + x1 * w1[3][nf];
        float iv = sig_(gi), fv = sig_(gf), gv = tanh_(gg), ov = sig_(go);
        int idx = n * HID + u;
        float cn = fv * c[idx] + iv * gv;
        c[idx] = cn;
        hout[idx] = f2bf(ov * tanh_(cn));
      }
    }
  }
}

// ---------------- FC1 incremental accumulation for timestep t ----------------
// acc[b][j] += sum_{a,h} hnew[2b+a][h] * fc1w[j][a*10240 + t*512 + h]
// A = hnew viewed as [4096][1024] (rows 2b,2b+1 contiguous). M=4096,N=512,K=1024.
// grid: 32 m-blocks (128 rows) x 16 j-blocks (32 cols) = 512 blocks.
__global__ __launch_bounds__(256, 2) void fc1_step(
    const u16* __restrict__ hin,   // [4096][1024] bf16 view
    const u16* __restrict__ fc1w,  // [512][20480] bf16
    float* __restrict__ acc,       // [4096][512]
    int t) {
  const int lane = threadIdx.x & 63;
  const int wid = threadIdx.x >> 6;
  const int j0 = (blockIdx.x & 15) * 32;
  const int m0 = (blockIdx.x >> 4) * 128 + wid * 32;
  const int jl = lane & 15;
  const int kg = (lane >> 4) * 8;

  const u16* ap0 = hin + (m0 + jl) * 1024 + kg;
  const u16* ap1 = ap0 + 16 * 1024;
  const u16* bbase = fc1w + (j0 + jl) * 20480 + t * 512;

  f32x4 af[2][2];
#pragma unroll
  for (int m = 0; m < 2; ++m)
#pragma unroll
    for (int nf = 0; nf < 2; ++nf) af[m][nf] = (f32x4){0.f, 0.f, 0.f, 0.f};

#pragma unroll 2
  for (int k0 = 0; k0 < 1024; k0 += 32) {
    bf16x8 a0 = ldb(ap0 + k0);
    bf16x8 a1 = ldb(ap1 + k0);
    int kk = k0 + kg;
    int boff = ((kk >> 9) * 10240) + (kk & 511);
#pragma unroll
    for (int nf = 0; nf < 2; ++nf) {
      bf16x8 b = ldb(bbase + nf * 16 * 20480 + boff);
      af[0][nf] = MFMA16(a0, b, af[0][nf]);
      af[1][nf] = MFMA16(a1, b, af[1][nf]);
    }
  }

#pragma unroll
  for (int m = 0; m < 2; ++m)
#pragma unroll
    for (int nf = 0; nf < 2; ++nf)
#pragma unroll
      for (int r = 0; r < 4; ++r) {
        int bb = m0 + m * 16 + (lane >> 4) * 4 + r;
        int j = j0 + nf * 16 + jl;
        acc[bb * 512 + j] += af[m][nf][r];
      }
}

// ---------------- head: relu(acc + b1) @ fc2^T + b2, sigmoid ----------------
__global__ __launch_bounds__(256) void head_kernel(
    const float* __restrict__ acc, const float* __restrict__ fc1b,
    const float* __restrict__ fc2w, const float* __restrict__ fc2b,
    float* __restrict__ out) {
  int lane = threadIdx.x & 63;
  int row = blockIdx.x * 4 + (threadIdx.x >> 6);
  float s = 0.f;
#pragma unroll
  for (int j = lane; j < 512; j += 64)
    s += fmaxf(acc[row * 512 + j] + fc1b[j], 0.f) * fc2w[j];
#pragma unroll
  for (int off = 32; off; off >>= 1) s += __shfl_down(s, off);
  if (lane == 0) out[row] = 1.f / (1.f + __expf(-(s + fc2b[0])));
}

extern "C" void kernel_launch(void* const* d_in, const int* in_sizes, int n_in,
                              void* d_out, int out_size, void* d_ws, size_t ws_size,
                              hipStream_t stream) {
  const float* x = (const float*)d_in[0];
  const float* h0 = (const float*)d_in[2];
  const float* c0 = (const float*)d_in[3];
  const float* Wih = (const float*)d_in[4];
  const float* Whh = (const float*)d_in[5];
  const float* bih = (const float*)d_in[6];
  const float* bhh = (const float*)d_in[7];
  const float* fc1w = (const float*)d_in[8];
  const float* fc1b = (const float*)d_in[9];
  const float* fc2w = (const float*)d_in[10];
  const float* fc2b = (const float*)d_in[11];
  float* out = (float*)d_out;

  char* ws = (char*)d_ws;
  const size_t MB = 1 << 20;
  u16* Whh_bf = (u16*)(ws);              //  2 MB: 2048*512 bf16
  u16* fc1_bf = (u16*)(ws + 2 * MB);     // 20 MB: 512*20480 bf16
  u16* hbf0 = (u16*)(ws + 22 * MB);      //  8 MB
  u16* hbf1 = (u16*)(ws + 30 * MB);      //  8 MB
  float* cws = (float*)(ws + 38 * MB);   // 16 MB
  float* acc = (float*)(ws + 54 * MB);   //  8 MB  (total 62 MB)

  convert_f32_bf16<<<1024, 256, 0, stream>>>(Whh, Whh_bf, 2048 * 512);
  convert_f32_bf16<<<10240, 256, 0, stream>>>(fc1w, fc1_bf, 512 * 20480);
  init_state<<<16384, 256, 0, stream>>>(h0, c0, hbf0, cws, acc, B2V * HID, NBATCH * HID);

  u16* hb[2] = {hbf0, hbf1};
  for (int t = 0; t < TSTEPS; ++t) {
    lstm_step<<<1024, 256, 0, stream>>>(Whh_bf, Wih, bih, bhh, x,
                                        hb[t & 1], hb[(t + 1) & 1], cws, t);
    fc1_step<<<512, 256, 0, stream>>>(hb[(t + 1) & 1], fc1_bf, acc, t);
  }
  head_kernel<<<1024, 256, 0, stream>>>(acc, fc1b, fc2w, fc2b, out);
}

// Round 3
// 1085.109 us; speedup vs baseline: 2.1849x; 2.1849x over previous
//
#include <hip/hip_runtime.h>
#include <hip/hip_bf16.h>

#define HID 512
#define B2V 8192
#define TSTEPS 20

typedef __bf16 bf16x8 __attribute__((ext_vector_type(8)));
typedef float f32x4 __attribute__((ext_vector_type(4)));
typedef unsigned short u16;

__device__ __forceinline__ u16 f2bf(float f) {
  unsigned u = __builtin_bit_cast(unsigned, f);
  u = (u + 0x7FFFu + ((u >> 16) & 1u)) >> 16;   // RNE
  return (u16)u;
}
__device__ __forceinline__ float sig_(float v) { return 1.f / (1.f + __expf(-v)); }
__device__ __forceinline__ float tanh_(float v) { return 1.f - 2.f / (1.f + __expf(2.f * v)); }

#define MFMA16(a, b, c) __builtin_amdgcn_mfma_f32_16x16x32_bf16((a), (b), (c), 0, 0, 0)

// async global->LDS, 16B per lane. LDS dest is wave-uniform base + lane*16.
__device__ __forceinline__ void gload16(const u16* g, u16* lds) {
#if defined(__HIP_DEVICE_COMPILE__)
  __builtin_amdgcn_global_load_lds(
      (const __attribute__((address_space(1))) unsigned*)g,
      (__attribute__((address_space(3))) unsigned*)lds,
      16, 0, 0);
#endif
}

// ---------------- prep kernels ----------------
__global__ void convert_f32_bf16(const float* __restrict__ s, u16* __restrict__ d, int n) {
  int i = (blockIdx.x * blockDim.x + threadIdx.x) * 4;
  if (i + 3 < n) {
    float4 v = *reinterpret_cast<const float4*>(s + i);
    ushort4 o;
    o.x = f2bf(v.x); o.y = f2bf(v.y); o.z = f2bf(v.z); o.w = f2bf(v.w);
    *reinterpret_cast<ushort4*>(d + i) = o;
  }
}

__global__ void init_state(const float* __restrict__ h0, const float* __restrict__ c0,
                           u16* __restrict__ hbf, float* __restrict__ cws,
                           float* __restrict__ acc, int n, int nacc) {
  int i = blockIdx.x * blockDim.x + threadIdx.x;
  if (i < n) { hbf[i] = f2bf(h0[i]); cws[i] = c0[i]; }
  if (i < nacc) acc[i] = 0.f;
}

// ---------------- fused step kernel ----------------
// blocks [0, nlstm): LSTM gates GEMM + activations for timestep t.
//   M=8192 x N=2048 (4 gates x 512 u), K=512. Block tile 128 x (4g x 32u).
// blocks [nlstm, ...): FC1 accumulation for timestep t-1 (reads same hin).
//   M=4096, N=512, K=1024. Block tile 128 x 128.
__global__ __launch_bounds__(256, 2) void step_kernel(
    const u16* __restrict__ Whh,    // [2048][512] bf16
    const float* __restrict__ Wih,  // [2048][2]
    const float* __restrict__ bih, const float* __restrict__ bhh,
    const float* __restrict__ x,    // [8192][20][2] f32
    const u16* __restrict__ hin,    // [8192][512] bf16 (= h(t); fc1 A as [4096][1024])
    u16* __restrict__ hout,         // [8192][512] bf16 (= h(t+1))
    float* __restrict__ c,          // [8192][512] f32
    const u16* __restrict__ fc1w,   // [512][20480] bf16
    float* __restrict__ facc,       // [4096][512] f32
    int t, int nlstm) {
  __shared__ u16 smem[16384];       // A: [128][64] (16KB) + B: [128][64] (16KB)
  u16* Alds = smem;
  u16* Blds = smem + 8192;

  const int tid = threadIdx.x;
  const int lane = tid & 63, wid = tid >> 6;
  const int jl = lane & 15, kg = lane >> 4;
  const int wm = wid >> 1, wn = wid & 1;
  const int srow = lane >> 3;                 // staging: row within 8-row call
  const int schunk = (lane & 7) ^ srow;       // pre-swizzled source chunk (involution)

  if ((int)blockIdx.x < nlstm) {
    // ================= LSTM gates =================
    const int bid = blockIdx.x;
    const int u0 = (bid & 15) * 32;
    const int n0 = (bid >> 4) * 128;

    f32x4 acc[4][4];                          // [m-tile][gate]
#pragma unroll
    for (int i = 0; i < 4; ++i)
#pragma unroll
      for (int j = 0; j < 4; ++j) acc[i][j] = (f32x4){0.f, 0.f, 0.f, 0.f};

    for (int k0 = 0; k0 < 512; k0 += 64) {
      if (k0) __syncthreads();
#pragma unroll
      for (int q = 0; q < 4; ++q) {           // stage A: 128 rows x 128B
        int r = (wid * 4 + q) * 8 + srow;
        gload16(hin + (n0 + r) * 512 + k0 + schunk * 8, Alds + (wid * 4 + q) * 512);
      }
#pragma unroll
      for (int q = 0; q < 4; ++q) {           // stage B: 4 gates x 32 u-rows x 128B
        int br = (wid * 4 + q) * 8 + srow;
        int g = br >> 5, ul = br & 31;
        gload16(Whh + (g * 512 + u0 + ul) * 512 + k0 + schunk * 8, Blds + (wid * 4 + q) * 512);
      }
      __syncthreads();                         // drains vmcnt -> LDS valid
#pragma unroll
      for (int kk = 0; kk < 2; ++kk) {
        const int cs = (kk * 4 + kg) ^ (jl & 7);
        bf16x8 a[4], b[4];
#pragma unroll
        for (int mt = 0; mt < 4; ++mt) {
          int row = wm * 64 + mt * 16 + jl;
          a[mt] = *reinterpret_cast<const bf16x8*>(Alds + row * 64 + cs * 8);
        }
#pragma unroll
        for (int g = 0; g < 4; ++g) {
          int br = g * 32 + wn * 16 + jl;
          b[g] = *reinterpret_cast<const bf16x8*>(Blds + br * 64 + cs * 8);
        }
#pragma unroll
        for (int mt = 0; mt < 4; ++mt)
#pragma unroll
          for (int g = 0; g < 4; ++g) acc[mt][g] = MFMA16(a[mt], b[g], acc[mt][g]);
      }
    }

    // ---- fused activation epilogue ----
    const int u = u0 + wn * 16 + jl;
    float eb[4], w0[4], w1[4];
#pragma unroll
    for (int g = 0; g < 4; ++g) {
      int j = g * 512 + u;
      eb[g] = bih[j] + bhh[j];
      w0[g] = Wih[j * 2 + 0];
      w1[g] = Wih[j * 2 + 1];
    }
#pragma unroll
    for (int mt = 0; mt < 4; ++mt) {
#pragma unroll
      for (int r = 0; r < 4; ++r) {
        int n = n0 + wm * 64 + mt * 16 + kg * 4 + r;
        float x0 = x[n * 40 + t * 2 + 0];
        float x1 = x[n * 40 + t * 2 + 1];
        float gi = acc[mt][0][r] + eb[0] + x0 * w0[0] + x1 * w1[0];
        float gf = acc[mt][1][r] + eb[1] + x0 * w0[1] + x1 * w1[1];
        float gg = acc[mt][2][r] + eb[2] + x0 * w0[2] + x1 * w1[2];
        float go = acc[mt][3][r] + eb[3] + x0 * w0[3] + x1 * w1[3];
        float iv = sig_(gi), fv = sig_(gf), gv = tanh_(gg), ov = sig_(go);
        int idx = n * 512 + u;
        float cn = fv * c[idx] + iv * gv;
        c[idx] = cn;
        hout[idx] = f2bf(ov * tanh_(cn));
      }
    }
  } else {
    // ================= FC1 accumulate (timestep t-1) =================
    const int bid = blockIdx.x - nlstm;
    const int ft = t - 1;
    const int j0 = (bid & 3) * 128;
    const int m0 = (bid >> 2) * 128;

    f32x4 acc[4][4];                          // [m-tile][n-tile]
#pragma unroll
    for (int i = 0; i < 4; ++i)
#pragma unroll
      for (int j = 0; j < 4; ++j) acc[i][j] = (f32x4){0.f, 0.f, 0.f, 0.f};

    for (int k0 = 0; k0 < 1024; k0 += 64) {
      if (k0) __syncthreads();
#pragma unroll
      for (int q = 0; q < 4; ++q) {           // stage A: h(t) as [4096][1024]
        int r = (wid * 4 + q) * 8 + srow;
        gload16(hin + (m0 + r) * 1024 + k0 + schunk * 8, Alds + (wid * 4 + q) * 512);
      }
      const int colb = ((k0 >> 9) * 10240) + ft * 512 + (k0 & 511) + schunk * 8;
#pragma unroll
      for (int q = 0; q < 4; ++q) {           // stage B: fc1w rows j0..j0+127
        int br = (wid * 4 + q) * 8 + srow;
        gload16(fc1w + (j0 + br) * 20480 + colb, Blds + (wid * 4 + q) * 512);
      }
      __syncthreads();
#pragma unroll
      for (int kk = 0; kk < 2; ++kk) {
        const int cs = (kk * 4 + kg) ^ (jl & 7);
        bf16x8 a[4], b[4];
#pragma unroll
        for (int mt = 0; mt < 4; ++mt) {
          int row = wm * 64 + mt * 16 + jl;
          a[mt] = *reinterpret_cast<const bf16x8*>(Alds + row * 64 + cs * 8);
        }
#pragma unroll
        for (int nt = 0; nt < 4; ++nt) {
          int br = wn * 64 + nt * 16 + jl;
          b[nt] = *reinterpret_cast<const bf16x8*>(Blds + br * 64 + cs * 8);
        }
#pragma unroll
        for (int mt = 0; mt < 4; ++mt)
#pragma unroll
          for (int nt = 0; nt < 4; ++nt) acc[mt][nt] = MFMA16(a[mt], b[nt], acc[mt][nt]);
      }
    }
#pragma unroll
    for (int mt = 0; mt < 4; ++mt)
#pragma unroll
      for (int nt = 0; nt < 4; ++nt) {
        int j = j0 + wn * 64 + nt * 16 + jl;
#pragma unroll
        for (int r = 0; r < 4; ++r) {
          int bb = m0 + wm * 64 + mt * 16 + kg * 4 + r;
          facc[bb * 512 + j] += acc[mt][nt][r];
        }
      }
  }
}

// ---------------- head: relu(acc + b1) @ fc2^T + b2, sigmoid ----------------
__global__ __launch_bounds__(256) void head_kernel(
    const float* __restrict__ acc, const float* __restrict__ fc1b,
    const float* __restrict__ fc2w, const float* __restrict__ fc2b,
    float* __restrict__ out) {
  int lane = threadIdx.x & 63;
  int row = blockIdx.x * 4 + (threadIdx.x >> 6);
  float s = 0.f;
#pragma unroll
  for (int j = lane; j < 512; j += 64)
    s += fmaxf(acc[row * 512 + j] + fc1b[j], 0.f) * fc2w[j];
#pragma unroll
  for (int off = 32; off; off >>= 1) s += __shfl_down(s, off);
  if (lane == 0) out[row] = 1.f / (1.f + __expf(-(s + fc2b[0])));
}

extern "C" void kernel_launch(void* const* d_in, const int* in_sizes, int n_in,
                              void* d_out, int out_size, void* d_ws, size_t ws_size,
                              hipStream_t stream) {
  const float* x = (const float*)d_in[0];
  const float* h0 = (const float*)d_in[2];
  const float* c0 = (const float*)d_in[3];
  const float* Wih = (const float*)d_in[4];
  const float* Whh = (const float*)d_in[5];
  const float* bih = (const float*)d_in[6];
  const float* bhh = (const float*)d_in[7];
  const float* fc1w = (const float*)d_in[8];
  const float* fc1b = (const float*)d_in[9];
  const float* fc2w = (const float*)d_in[10];
  const float* fc2b = (const float*)d_in[11];
  float* out = (float*)d_out;

  char* ws = (char*)d_ws;
  const size_t MB = 1 << 20;
  u16* Whh_bf = (u16*)(ws);              //  2 MB
  u16* fc1_bf = (u16*)(ws + 2 * MB);     // 20 MB
  u16* hbf0 = (u16*)(ws + 22 * MB);      //  8 MB
  u16* hbf1 = (u16*)(ws + 30 * MB);      //  8 MB
  float* cws = (float*)(ws + 38 * MB);   // 16 MB
  float* facc = (float*)(ws + 54 * MB);  //  8 MB

  convert_f32_bf16<<<1024, 256, 0, stream>>>(Whh, Whh_bf, 2048 * 512);
  convert_f32_bf16<<<10240, 256, 0, stream>>>(fc1w, fc1_bf, 512 * 20480);
  init_state<<<16384, 256, 0, stream>>>(h0, c0, hbf0, cws, facc, B2V * HID, 4096 * HID);

  u16* hb[2] = {hbf0, hbf1};
  for (int t = 0; t < TSTEPS; ++t) {
    int grid = 1024 + (t > 0 ? 128 : 0);
    step_kernel<<<grid, 256, 0, stream>>>(Whh_bf, Wih, bih, bhh, x,
                                          hb[t & 1], hb[(t + 1) & 1], cws,
                                          fc1_bf, facc, t, 1024);
  }
  // final fc1 for t=19 reads hb[20&1] = hb[0]
  step_kernel<<<128, 256, 0, stream>>>(Whh_bf, Wih, bih, bhh, x,
                                       hb[0], hb[1], cws, fc1_bf, facc, 20, 0);
  head_kernel<<<1024, 256, 0, stream>>>(facc, fc1b, fc2w, fc2b, out);
}

// Round 4
// 910.553 us; speedup vs baseline: 2.6038x; 1.1917x over previous
//
#include <hip/hip_runtime.h>
#include <hip/hip_bf16.h>

#define HID 512
#define B2V 8192
#define TSTEPS 20

typedef __bf16 bf16x8 __attribute__((ext_vector_type(8)));
typedef float f32x4 __attribute__((ext_vector_type(4)));
typedef unsigned short u16;

__device__ __forceinline__ u16 f2bf(float f) {
  unsigned u = __builtin_bit_cast(unsigned, f);
  u = (u + 0x7FFFu + ((u >> 16) & 1u)) >> 16;   // RNE
  return (u16)u;
}
__device__ __forceinline__ float sig_(float v) { return 1.f / (1.f + __expf(-v)); }
__device__ __forceinline__ float tanh_(float v) { return 1.f - 2.f / (1.f + __expf(2.f * v)); }

#define MFMA16(a, b, c) __builtin_amdgcn_mfma_f32_16x16x32_bf16((a), (b), (c), 0, 0, 0)

// async global->LDS, 16B per lane. LDS dest is wave-uniform base + lane*16.
__device__ __forceinline__ void gload16(const u16* g, u16* lds) {
#if defined(__HIP_DEVICE_COMPILE__)
  __builtin_amdgcn_global_load_lds(
      (const __attribute__((address_space(1))) unsigned*)g,
      (__attribute__((address_space(3))) unsigned*)lds,
      16, 0, 0);
#endif
}

// ---------------- prep kernels ----------------
__global__ void convert_f32_bf16(const float* __restrict__ s, u16* __restrict__ d, int n) {
  int i = (blockIdx.x * blockDim.x + threadIdx.x) * 4;
  if (i + 3 < n) {
    float4 v = *reinterpret_cast<const float4*>(s + i);
    ushort4 o;
    o.x = f2bf(v.x); o.y = f2bf(v.y); o.z = f2bf(v.z); o.w = f2bf(v.w);
    *reinterpret_cast<ushort4*>(d + i) = o;
  }
}

__global__ void init_state(const float* __restrict__ h0, const float* __restrict__ c0,
                           u16* __restrict__ hbf, float* __restrict__ cws,
                           float* __restrict__ acc, int n, int nacc) {
  int i = blockIdx.x * blockDim.x + threadIdx.x;
  if (i < n) { hbf[i] = f2bf(h0[i]); cws[i] = c0[i]; }
  if (i < nacc) acc[i] = 0.f;
}

// ---------------- fused step kernel ----------------
// blocks [0, nlstm): LSTM gates GEMM + activations for timestep t.
//   M=8192 x N=2048 (4 gates x 512 u), K=512. Block tile 128 x (4g x 32u).
// blocks [nlstm, ...): FC1 accumulation for timestep t-1 (reads same hin).
//   M=4096, N=512, K=1024. Block tile 128 x 128.
// K-loop: double-buffered LDS, stage(k+1) issued BEFORE compute(k), ONE
// barrier per K-step (compiler emits vmcnt(0) before s_barrier -> buffer
// k+1 is valid; lgkmcnt(0) -> all ds_reads of buffer k done before overwrite).
// Block mapping is XCD-pinned (xcd = bid&7 heuristic): XCD x owns n-rows
// [1024x, 1024x+1024) for lstm AND the matching fc1 m-rows, so hin/c/hout
// slices stay in its L2 across all 20 dispatches.
__global__ __launch_bounds__(256, 2) void step_kernel(
    const u16* __restrict__ Whh,    // [2048][512] bf16
    const float* __restrict__ Wih,  // [2048][2]
    const float* __restrict__ bih, const float* __restrict__ bhh,
    const float* __restrict__ x,    // [8192][20][2] f32
    const u16* __restrict__ hin,    // [8192][512] bf16 (= h(t); fc1 A as [4096][1024])
    u16* __restrict__ hout,         // [8192][512] bf16 (= h(t+1))
    float* __restrict__ c,          // [8192][512] f32
    const u16* __restrict__ fc1w,   // [512][20480] bf16
    float* __restrict__ facc,       // [4096][512] f32
    int t, int nlstm) {
  __shared__ u16 smem[32768];       // 2 buffers x (A[128][64] + B[128][64]) = 64 KB

  const int tid = threadIdx.x;
  const int lane = tid & 63, wid = tid >> 6;
  const int jl = lane & 15, kg = lane >> 4;
  const int wm = wid >> 1, wn = wid & 1;
  const int srow = lane >> 3;                 // staging: row within 8-row call
  const int schunk = (lane & 7) ^ srow;       // pre-swizzled source chunk (involution)

  if ((int)blockIdx.x < nlstm) {
    // ================= LSTM gates =================
    const int bid = blockIdx.x;
    const int xcd = bid & 7, q8 = bid >> 3;   // XCD-pinned bijective remap (1024 = 8*128)
    const int n0 = (xcd * 8 + (q8 & 7)) * 128;
    const int u0 = (q8 >> 3) * 32;

    f32x4 acc[4][4];                          // [m-tile][gate]
#pragma unroll
    for (int i = 0; i < 4; ++i)
#pragma unroll
      for (int j = 0; j < 4; ++j) acc[i][j] = (f32x4){0.f, 0.f, 0.f, 0.f};

    // prologue: stage K-tile 0 into buffer 0
#pragma unroll
    for (int q = 0; q < 4; ++q) {
      int r = (wid * 4 + q) * 8 + srow;
      gload16(hin + (n0 + r) * 512 + schunk * 8, smem + (wid * 4 + q) * 512);
    }
#pragma unroll
    for (int q = 0; q < 4; ++q) {
      int br = (wid * 4 + q) * 8 + srow;
      int g = br >> 5, ul = br & 31;
      gload16(Whh + (g * 512 + u0 + ul) * 512 + schunk * 8,
              smem + 8192 + (wid * 4 + q) * 512);
    }
    __syncthreads();

    for (int ks = 0; ks < 8; ++ks) {
      const int cur = ks & 1;
      u16* Acur = smem + cur * 16384;
      u16* Bcur = Acur + 8192;
      if (ks < 7) {                           // stage K-tile ks+1 into other buffer
        u16* Anxt = smem + (cur ^ 1) * 16384;
        const int kn = (ks + 1) * 64;
#pragma unroll
        for (int q = 0; q < 4; ++q) {
          int r = (wid * 4 + q) * 8 + srow;
          gload16(hin + (n0 + r) * 512 + kn + schunk * 8, Anxt + (wid * 4 + q) * 512);
        }
#pragma unroll
        for (int q = 0; q < 4; ++q) {
          int br = (wid * 4 + q) * 8 + srow;
          int g = br >> 5, ul = br & 31;
          gload16(Whh + (g * 512 + u0 + ul) * 512 + kn + schunk * 8,
                  Anxt + 8192 + (wid * 4 + q) * 512);
        }
      }
#pragma unroll
      for (int kk = 0; kk < 2; ++kk) {
        const int cs = (kk * 4 + kg) ^ (jl & 7);
        bf16x8 a[4], b[4];
#pragma unroll
        for (int mt = 0; mt < 4; ++mt) {
          int row = wm * 64 + mt * 16 + jl;
          a[mt] = *reinterpret_cast<const bf16x8*>(Acur + row * 64 + cs * 8);
        }
#pragma unroll
        for (int g = 0; g < 4; ++g) {
          int br = g * 32 + wn * 16 + jl;
          b[g] = *reinterpret_cast<const bf16x8*>(Bcur + br * 64 + cs * 8);
        }
#pragma unroll
        for (int mt = 0; mt < 4; ++mt)
#pragma unroll
          for (int g = 0; g < 4; ++g) acc[mt][g] = MFMA16(a[mt], b[g], acc[mt][g]);
      }
      __syncthreads();
    }

    // ---- fused activation epilogue ----
    const int u = u0 + wn * 16 + jl;
    float eb[4], w0[4], w1[4];
#pragma unroll
    for (int g = 0; g < 4; ++g) {
      int j = g * 512 + u;
      eb[g] = bih[j] + bhh[j];
      w0[g] = Wih[j * 2 + 0];
      w1[g] = Wih[j * 2 + 1];
    }
#pragma unroll
    for (int mt = 0; mt < 4; ++mt) {
#pragma unroll
      for (int r = 0; r < 4; ++r) {
        int n = n0 + wm * 64 + mt * 16 + kg * 4 + r;
        float x0 = x[n * 40 + t * 2 + 0];
        float x1 = x[n * 40 + t * 2 + 1];
        float gi = acc[mt][0][r] + eb[0] + x0 * w0[0] + x1 * w1[0];
        float gf = acc[mt][1][r] + eb[1] + x0 * w0[1] + x1 * w1[1];
        float gg = acc[mt][2][r] + eb[2] + x0 * w0[2] + x1 * w1[2];
        float go = acc[mt][3][r] + eb[3] + x0 * w0[3] + x1 * w1[3];
        float iv = sig_(gi), fv = sig_(gf), gv = tanh_(gg), ov = sig_(go);
        int idx = n * 512 + u;
        float cn = fv * c[idx] + iv * gv;
        c[idx] = cn;
        hout[idx] = f2bf(ov * tanh_(cn));
      }
    }
  } else {
    // ================= FC1 accumulate (timestep t-1) =================
    const int bid = blockIdx.x - nlstm;       // 0..127
    const int ft = t - 1;
    const int xcd = bid & 7, q8 = bid >> 3;   // XCD-pinned bijective remap (128 = 8*16)
    const int m0 = (xcd * 4 + (q8 & 3)) * 128;
    const int j0 = (q8 >> 2) * 128;

    f32x4 acc[4][4];                          // [m-tile][n-tile]
#pragma unroll
    for (int i = 0; i < 4; ++i)
#pragma unroll
      for (int j = 0; j < 4; ++j) acc[i][j] = (f32x4){0.f, 0.f, 0.f, 0.f};

    // prologue: stage K-tile 0 into buffer 0
#pragma unroll
    for (int q = 0; q < 4; ++q) {
      int r = (wid * 4 + q) * 8 + srow;
      gload16(hin + (m0 + r) * 1024 + schunk * 8, smem + (wid * 4 + q) * 512);
    }
    {
      const int colb0 = ft * 512 + schunk * 8;
#pragma unroll
      for (int q = 0; q < 4; ++q) {
        int br = (wid * 4 + q) * 8 + srow;
        gload16(fc1w + (j0 + br) * 20480 + colb0, smem + 8192 + (wid * 4 + q) * 512);
      }
    }
    __syncthreads();

    for (int ks = 0; ks < 16; ++ks) {
      const int cur = ks & 1;
      u16* Acur = smem + cur * 16384;
      u16* Bcur = Acur + 8192;
      if (ks < 15) {
        u16* Anxt = smem + (cur ^ 1) * 16384;
        const int kn = (ks + 1) * 64;
#pragma unroll
        for (int q = 0; q < 4; ++q) {
          int r = (wid * 4 + q) * 8 + srow;
          gload16(hin + (m0 + r) * 1024 + kn + schunk * 8, Anxt + (wid * 4 + q) * 512);
        }
        const int colb = ((kn >> 9) * 10240) + ft * 512 + (kn & 511) + schunk * 8;
#pragma unroll
        for (int q = 0; q < 4; ++q) {
          int br = (wid * 4 + q) * 8 + srow;
          gload16(fc1w + (j0 + br) * 20480 + colb, Anxt + 8192 + (wid * 4 + q) * 512);
        }
      }
#pragma unroll
      for (int kk = 0; kk < 2; ++kk) {
        const int cs = (kk * 4 + kg) ^ (jl & 7);
        bf16x8 a[4], b[4];
#pragma unroll
        for (int mt = 0; mt < 4; ++mt) {
          int row = wm * 64 + mt * 16 + jl;
          a[mt] = *reinterpret_cast<const bf16x8*>(Acur + row * 64 + cs * 8);
        }
#pragma unroll
        for (int nt = 0; nt < 4; ++nt) {
          int br = wn * 64 + nt * 16 + jl;
          b[nt] = *reinterpret_cast<const bf16x8*>(Bcur + br * 64 + cs * 8);
        }
#pragma unroll
        for (int mt = 0; mt < 4; ++mt)
#pragma unroll
          for (int nt = 0; nt < 4; ++nt) acc[mt][nt] = MFMA16(a[mt], b[nt], acc[mt][nt]);
      }
      __syncthreads();
    }
#pragma unroll
    for (int mt = 0; mt < 4; ++mt)
#pragma unroll
      for (int nt = 0; nt < 4; ++nt) {
        int j = j0 + wn * 64 + nt * 16 + jl;
#pragma unroll
        for (int r = 0; r < 4; ++r) {
          int bb = m0 + wm * 64 + mt * 16 + kg * 4 + r;
          facc[bb * 512 + j] += acc[mt][nt][r];
        }
      }
  }
}

// ---------------- head: relu(acc + b1) @ fc2^T + b2, sigmoid ----------------
__global__ __launch_bounds__(256) void head_kernel(
    const float* __restrict__ acc, const float* __restrict__ fc1b,
    const float* __restrict__ fc2w, const float* __restrict__ fc2b,
    float* __restrict__ out) {
  int lane = threadIdx.x & 63;
  int row = blockIdx.x * 4 + (threadIdx.x >> 6);
  float s = 0.f;
#pragma unroll
  for (int j = lane; j < 512; j += 64)
    s += fmaxf(acc[row * 512 + j] + fc1b[j], 0.f) * fc2w[j];
#pragma unroll
  for (int off = 32; off; off >>= 1) s += __shfl_down(s, off);
  if (lane == 0) out[row] = 1.f / (1.f + __expf(-(s + fc2b[0])));
}

extern "C" void kernel_launch(void* const* d_in, const int* in_sizes, int n_in,
                              void* d_out, int out_size, void* d_ws, size_t ws_size,
                              hipStream_t stream) {
  const float* x = (const float*)d_in[0];
  const float* h0 = (const float*)d_in[2];
  const float* c0 = (const float*)d_in[3];
  const float* Wih = (const float*)d_in[4];
  const float* Whh = (const float*)d_in[5];
  const float* bih = (const float*)d_in[6];
  const float* bhh = (const float*)d_in[7];
  const float* fc1w = (const float*)d_in[8];
  const float* fc1b = (const float*)d_in[9];
  const float* fc2w = (const float*)d_in[10];
  const float* fc2b = (const float*)d_in[11];
  float* out = (float*)d_out;

  char* ws = (char*)d_ws;
  const size_t MB = 1 << 20;
  u16* Whh_bf = (u16*)(ws);              //  2 MB
  u16* fc1_bf = (u16*)(ws + 2 * MB);     // 20 MB
  u16* hbf0 = (u16*)(ws + 22 * MB);      //  8 MB
  u16* hbf1 = (u16*)(ws + 30 * MB);      //  8 MB
  float* cws = (float*)(ws + 38 * MB);   // 16 MB
  float* facc = (float*)(ws + 54 * MB);  //  8 MB

  convert_f32_bf16<<<1024, 256, 0, stream>>>(Whh, Whh_bf, 2048 * 512);
  convert_f32_bf16<<<10240, 256, 0, stream>>>(fc1w, fc1_bf, 512 * 20480);
  init_state<<<16384, 256, 0, stream>>>(h0, c0, hbf0, cws, facc, B2V * HID, 4096 * HID);

  u16* hb[2] = {hbf0, hbf1};
  for (int t = 0; t < TSTEPS; ++t) {
    int grid = 1024 + (t > 0 ? 128 : 0);
    step_kernel<<<grid, 256, 0, stream>>>(Whh_bf, Wih, bih, bhh, x,
                                          hb[t & 1], hb[(t + 1) & 1], cws,
                                          fc1_bf, facc, t, 1024);
  }
  // final fc1 for t=19 reads hb[20&1] = hb[0]
  step_kernel<<<128, 256, 0, stream>>>(Whh_bf, Wih, bih, bhh, x,
                                       hb[0], hb[1], cws, fc1_bf, facc, 20, 0);
  head_kernel<<<1024, 256, 0, stream>>>(facc, fc1b, fc2w, fc2b, out);
}